// Round 15
// baseline (33.266 us; speedup 1.0000x reference)
//
#include <hip/hip_runtime.h>
#include <stdint.h>

// Problem constants (fixed by the reference's setup_inputs / _make_edge_index)
static constexpr uint32_t NNODES = 2048;
static constexpr uint32_t NFEAT  = 128;
static constexpr uint32_t ODEG   = 8;
static constexpr uint32_t NE     = NNODES * ODEG;   // 16384 edges
static constexpr uint32_t NLG    = NE * ODEG;       // 131072 line-graph edges

// d_out: 38,010,880 float32 slots, RETURN ORDER (verified; absmax=0 @ R11/R13/R14):
//   new_x        : slots [0,          4,194,304)
//   lg_edge_index: slots [4,194,304,  4,456,448)
//   lg_edge_attr : slots [4,456,448, 38,010,880)
// One unit = 4 slots = one 16B store, true f32 values.
static constexpr uint32_t U4_NEWX = NE * 2u * NFEAT / 4u;   // 1,048,576 units
static constexpr uint32_t U4_IDX  = 2u * NLG / 4u;          //    65,536 units
static constexpr uint32_t U4_ATTR = NLG * 2u * NFEAT / 4u;  // 8,388,608 units
static constexpr uint32_t U4_TOT  = U4_NEWX + U4_IDX + U4_ATTR; // 9,502,720

// Persistent geometry: each block owns a contiguous 4096-unit span (64 KB of
// stores), processed in 16 iterations of 256 units. 9,502,720/4096 = 2320
// blocks (%8==0). Segment boundaries at 256 / 16 / 2048 blocks -> block-uniform.
static constexpr uint32_t SPAN   = 4096;                    // units per block
static constexpr uint32_t ITERS  = SPAN / 256u;             // 16
static constexpr uint32_t NBLK   = U4_TOT / SPAN;           // 2,320
static constexpr uint32_t CHUNK  = NBLK / 8u;               // 290
static constexpr uint32_t B_NEWX = U4_NEWX / SPAN;          // 256 blocks
static constexpr uint32_t B_IDX  = U4_IDX / SPAN;           //  16 blocks

// Native clang vector type — required by __builtin_nontemporal_store.
typedef float fx4 __attribute__((ext_vector_type(4)));

// Edge structure, closed-form: u_i = i>>3 ; v_i = (u_i + (i&7) + 1) mod 2048
__device__ __forceinline__ uint32_t edge_v(uint32_t i) {
  return ((i >> 3) + (i & 7u) + 1u) & (NNODES - 1u);
}

__device__ __forceinline__ fx4 avg4(float4 xv, float4 ev) {
  fx4 o;
  o.x = (xv.x + ev.x) * 0.5f;
  o.y = (xv.y + ev.y) * 0.5f;
  o.z = (xv.z + ev.z) * 0.5f;
  o.w = (xv.w + ev.w) * 0.5f;
  return o;
}
__device__ __forceinline__ void st_nt16(float4* p, fx4 v) {
  __builtin_nontemporal_store(v, reinterpret_cast<fx4*>(p));
}

__global__ __launch_bounds__(256) void g2lg_fused(const float4* __restrict__ x4,
                                                  const float4* __restrict__ ea4,
                                                  float4*       __restrict__ outv) {
  // XCD-chunked bijective swizzle (T1): XCD k gets blocks [k*CHUNK,(k+1)*CHUNK)
  // of contiguous spans -> per-XCD read working set ~2 MB (fits 4 MB L2).
  uint32_t wg = blockIdx.x;
  uint32_t b  = (wg & 7u) * CHUNK + (wg >> 3);
  uint32_t u0 = b * SPAN + threadIdx.x;

  if (b < B_NEWX) {
    // new_x[i, c]; c<128: (x[u_i]+ea[i][c])/2 ; c>=128: (x[v_i]+ea[i][c-128])/2
#pragma unroll 4
    for (uint32_t it = 0; it < ITERS; ++it) {
      uint32_t u  = u0 + it * 256u;
      uint32_t base = u * 4u;
      uint32_t i  = base >> 8;
      uint32_t c0 = base & 255u;
      uint32_t f0 = c0 & 127u;
      uint32_t xrow = (c0 < 128u) ? (i >> 3) : edge_v(i);
      st_nt16(outv + u, avg4(x4[xrow * (NFEAT / 4u) + f0 / 4u],
                             ea4[i    * (NFEAT / 4u) + f0 / 4u]));
    }
  } else if (b < B_NEWX + B_IDX) {
    // lg_edge_index (2, NLG): row0 li[e]=e>>3 ; row1 lj[e]=v_{e>>3}*8+(e&7)
#pragma unroll 4
    for (uint32_t it = 0; it < ITERS; ++it) {
      uint32_t u  = u0 + it * 256u;
      uint32_t base = (u - U4_NEWX) * 4u;   // multiple of 4
      uint32_t e0 = base & (NLG - 1u);
      uint32_t i  = e0 >> 3;
      fx4 o;
      if (base < NLG) {                     // li row: all 4 values = i
        float w = (float)i;
        o.x = w; o.y = w; o.z = w; o.w = w;
      } else {                              // lj row: v_i*8 + k0..k0+3
        float j0 = (float)(edge_v(i) * ODEG + (e0 & 7u));
        o.x = j0; o.y = j0 + 1.0f; o.z = j0 + 2.0f; o.w = j0 + 3.0f;
      }
      st_nt16(outv + u, o);
    }
  } else {
    // lg_edge_attr[e, c]: i=e>>3, k=e&7, vi=v_i
    //   c<128: (x[vi]+ea[i][c])/2 ; c>=128: (x[vi]+ea[vi*8+k][c-128])/2
#pragma unroll 4
    for (uint32_t it = 0; it < ITERS; ++it) {
      uint32_t u  = u0 + it * 256u;
      uint32_t base = (u - (U4_NEWX + U4_IDX)) * 4u;
      uint32_t e  = base >> 8;
      uint32_t c0 = base & 255u;
      uint32_t f0 = c0 & 127u;
      uint32_t i  = e >> 3;
      uint32_t k  = e & 7u;
      uint32_t vi = edge_v(i);
      uint32_t earow = (c0 < 128u) ? i : (vi * ODEG + k);
      st_nt16(outv + u, avg4(x4[vi    * (NFEAT / 4u) + f0 / 4u],
                             ea4[earow * (NFEAT / 4u) + f0 / 4u]));
    }
  }
}

extern "C" void kernel_launch(void* const* d_in, const int* in_sizes, int n_in,
                              void* d_out, int out_size, void* d_ws, size_t ws_size,
                              hipStream_t stream) {
  // Robust input assignment: x has 262,144 elements, edge_attr has 2,097,152.
  const float4* x4;
  const float4* ea4;
  if (in_sizes[0] == (int)(NNODES * NFEAT)) {
    x4  = (const float4*)d_in[0];
    ea4 = (const float4*)d_in[1];
  } else {
    x4  = (const float4*)d_in[1];
    ea4 = (const float4*)d_in[0];
  }
  float4* outv = (float4*)d_out;
  g2lg_fused<<<dim3(NBLK), dim3(256), 0, stream>>>(x4, ea4, outv);
}

// Round 16
// 30.409 us; speedup vs baseline: 1.0939x; 1.0939x over previous
//
#include <hip/hip_runtime.h>
#include <stdint.h>

// Problem constants (fixed by the reference's setup_inputs / _make_edge_index)
static constexpr uint32_t NNODES = 2048;
static constexpr uint32_t NFEAT  = 128;
static constexpr uint32_t ODEG   = 8;
static constexpr uint32_t NE     = NNODES * ODEG;   // 16384 edges
static constexpr uint32_t NLG    = NE * ODEG;       // 131072 line-graph edges

// d_out: 38,010,880 float32 slots, RETURN ORDER (verified; absmax=0 since R11):
//   new_x        : slots [0,          4,194,304)
//   lg_edge_index: slots [4,194,304,  4,456,448)
//   lg_edge_attr : slots [4,456,448, 38,010,880)
// One unit = 4 slots = one 16B store, true f32 values.
//
// MEASURED-BEST configuration (R13, 30.49 µs): fused single kernel,
// 1 unit/thread, XCD-bijective chunk swizzle, single 16B NT store.
// Refuted alternatives: per-component NT (R9, -34µs), bf16 packing (R10/R11
// no gain vs f32), 4x batching (R14, ±0), persistent SPAN=4096 (R15, -2.8µs).
// Mixed roofline ~24.5µs kernel + ~4µs replay overhead => ~30.5 is ~93% of
// achievable; remaining gap = HBM read/write turnaround.
static constexpr uint32_t U4_NEWX = NE * 2u * NFEAT / 4u;   // 1,048,576 units
static constexpr uint32_t U4_IDX  = 2u * NLG / 4u;          //    65,536 units
static constexpr uint32_t U4_ATTR = NLG * 2u * NFEAT / 4u;  // 8,388,608 units
static constexpr uint32_t U4_TOT  = U4_NEWX + U4_IDX + U4_ATTR; // 9,502,720
static constexpr uint32_t NWG     = U4_TOT / 256u;          // 37,120 (% 8 == 0)
static constexpr uint32_t CHUNK   = NWG / 8u;               // 4,640

// Native clang vector type — required by __builtin_nontemporal_store.
typedef float fx4 __attribute__((ext_vector_type(4)));

// Edge structure, closed-form: u_i = i>>3 ; v_i = (u_i + (i&7) + 1) mod 2048
__device__ __forceinline__ uint32_t edge_v(uint32_t i) {
  return ((i >> 3) + (i & 7u) + 1u) & (NNODES - 1u);
}

__device__ __forceinline__ fx4 avg4(float4 xv, float4 ev) {
  fx4 o;
  o.x = (xv.x + ev.x) * 0.5f;
  o.y = (xv.y + ev.y) * 0.5f;
  o.z = (xv.z + ev.z) * 0.5f;
  o.w = (xv.w + ev.w) * 0.5f;
  return o;
}
__device__ __forceinline__ void st_nt16(float4* p, fx4 v) {
  __builtin_nontemporal_store(v, reinterpret_cast<fx4*>(p));
}

__global__ __launch_bounds__(256) void g2lg_fused(const float4* __restrict__ x4,
                                                  const float4* __restrict__ ea4,
                                                  float4*       __restrict__ outv) {
  // XCD-chunked bijective swizzle (T1): dispatch d -> XCD d%8 (round-robin HW),
  // so XCD k processes contiguous work [k*CHUNK, (k+1)*CHUNK) blocks.
  uint32_t wg  = blockIdx.x;
  uint32_t swz = (wg & 7u) * CHUNK + (wg >> 3);
  uint32_t u   = swz * 256u + threadIdx.x;

  if (u < U4_NEWX) {
    // new_x[i, c]; c<128: (x[u_i]+ea[i][c])/2 ; c>=128: (x[v_i]+ea[i][c-128])/2
    uint32_t base = u * 4u;
    uint32_t i  = base >> 8;          // edge id
    uint32_t c0 = base & 255u;
    uint32_t f0 = c0 & 127u;          // multiple of 4
    uint32_t xrow = (c0 < 128u) ? (i >> 3) : edge_v(i);
    st_nt16(outv + u, avg4(x4[xrow * (NFEAT / 4u) + f0 / 4u],
                           ea4[i    * (NFEAT / 4u) + f0 / 4u]));
  } else if (u < U4_NEWX + U4_IDX) {
    // lg_edge_index (2, NLG): row0 li[e]=e>>3 ; row1 lj[e]=v_{e>>3}*8+(e&7)
    uint32_t base = (u - U4_NEWX) * 4u;   // [0, 262144), multiple of 4
    uint32_t e0 = base & (NLG - 1u);
    uint32_t i  = e0 >> 3;
    fx4 o;
    if (base < NLG) {                     // li row: all 4 values = i
      float w = (float)i;
      o.x = w; o.y = w; o.z = w; o.w = w;
    } else {                              // lj row: v_i*8 + k0..k0+3
      float j0 = (float)(edge_v(i) * ODEG + (e0 & 7u));
      o.x = j0; o.y = j0 + 1.0f; o.z = j0 + 2.0f; o.w = j0 + 3.0f;
    }
    st_nt16(outv + u, o);
  } else {
    // lg_edge_attr[e, c]: i=e>>3, k=e&7, vi=v_i
    //   c<128: (x[vi]+ea[i][c])/2 ; c>=128: (x[vi]+ea[vi*8+k][c-128])/2
    uint32_t base = (u - (U4_NEWX + U4_IDX)) * 4u;
    uint32_t e  = base >> 8;
    uint32_t c0 = base & 255u;
    uint32_t f0 = c0 & 127u;
    uint32_t i  = e >> 3;
    uint32_t k  = e & 7u;
    uint32_t vi = edge_v(i);
    uint32_t earow = (c0 < 128u) ? i : (vi * ODEG + k);
    st_nt16(outv + u, avg4(x4[vi    * (NFEAT / 4u) + f0 / 4u],
                           ea4[earow * (NFEAT / 4u) + f0 / 4u]));
  }
}

extern "C" void kernel_launch(void* const* d_in, const int* in_sizes, int n_in,
                              void* d_out, int out_size, void* d_ws, size_t ws_size,
                              hipStream_t stream) {
  // Robust input assignment: x has 262,144 elements, edge_attr has 2,097,152.
  const float4* x4;
  const float4* ea4;
  if (in_sizes[0] == (int)(NNODES * NFEAT)) {
    x4  = (const float4*)d_in[0];
    ea4 = (const float4*)d_in[1];
  } else {
    x4  = (const float4*)d_in[1];
    ea4 = (const float4*)d_in[0];
  }
  float4* outv = (float4*)d_out;
  g2lg_fused<<<dim3(NWG), dim3(256), 0, stream>>>(x4, ea4, outv);
}